// Round 1
// baseline (429.295 us; speedup 1.0000x reference)
//
#include <hip/hip_runtime.h>

// SpatialCrossAttention (BEVFormer SCA) fused pipeline for MI355X/gfx950.
// Stages:
//  K0 detect  : infer bev_mask storage layout (u8 / i32 / f32) from byte pattern
//  K1 hit     : hit[c][q] = any_d(mask), invcnt[q] = 1/max(sum_c hit,1)
//  K2 prep    : bf16 B-fragment tables for the 3 GEMMs (+ concat bias for off|attn)
//  G1 gemm<0> : vproj = value @ w_value + b_value  -> bf16 [139200][256]
//  G2 gemm<1> : offattn = query @ [w_off|w_attn] + [b_off|b_attn] -> f32 [10000][192]
//  K4 sample  : fused softmax + bilinear gather + cam-average -> slots f32 [10000][256]
//  G3 gemm<2> : out = slots @ w_out + b_out + query -> d_out f32

typedef __attribute__((ext_vector_type(8))) short short8;
typedef __attribute__((ext_vector_type(4))) short short4v;
typedef __attribute__((ext_vector_type(4))) float f32x4;

__device__ __forceinline__ short f2bf(float f) {
    union { float f; unsigned u; } c; c.f = f;
    unsigned u = c.u;
    unsigned r = (u + 0x7FFFu + ((u >> 16) & 1u)) >> 16;  // RNE
    return (short)r;
}
__device__ __forceinline__ float bf2f(short s) {
    union { unsigned u; float f; } c;
    c.u = ((unsigned)(unsigned short)s) << 16;
    return c.f;
}

static constexpr int QN   = 10000;
static constexpr int CAMS = 6;
static constexpr int NV   = 23200;   // 116*200
static constexpr int HH   = 116;
static constexpr int WW   = 200;
static constexpr int MROW = CAMS * NV;  // 139200

// ---------------- K0: mask layout detect ----------------
// u8 bool: ~30% of ALL bytes nonzero -> offsets %4==1/2 hit.
// i32 0/1: only offsets %4==0 nonzero.
// f32 0/1.0: bytes %4==3 are 0x3F for ones.
__global__ void detect_kernel(const unsigned char* __restrict__ mask, int* __restrict__ flag) {
    __shared__ unsigned s12[256], s3[256];
    unsigned o12 = 0, o3 = 0;
    for (int i = threadIdx.x; i < 65536; i += 256) {
        unsigned char b = mask[i];
        int m = i & 3;
        if (m == 1 || m == 2) o12 |= b;
        else if (m == 3) o3 |= b;
    }
    s12[threadIdx.x] = o12; s3[threadIdx.x] = o3;
    __syncthreads();
    if (threadIdx.x == 0) {
        unsigned a = 0, b = 0;
        for (int i = 0; i < 256; i++) { a |= s12[i]; b |= s3[i]; }
        *flag = a ? 0 : (b ? 2 : 1);  // 0=u8, 1=i32, 2=f32
    }
}

// ---------------- K1: hit / invcount ----------------
__global__ void hit_kernel(const void* __restrict__ mask, const int* __restrict__ flag,
                           float* __restrict__ hit, float* __restrict__ invcnt) {
    int q = blockIdx.x * 256 + threadIdx.x;
    if (q >= QN) return;
    int f = *flag;
    int cnt = 0;
    for (int c = 0; c < CAMS; c++) {
        bool any = false;
        #pragma unroll
        for (int d = 0; d < 4; d++) {
            size_t i = (size_t)(c * QN + q) * 4 + d;
            bool b;
            if (f == 0)      b = ((const unsigned char*)mask)[i] != 0;
            else if (f == 1) b = ((const int*)mask)[i] != 0;
            else             b = ((const float*)mask)[i] != 0.f;
            any |= b;
        }
        hit[c * QN + q] = any ? 1.f : 0.f;
        cnt += any ? 1 : 0;
    }
    invcnt[q] = 1.f / (float)(cnt > 0 ? cnt : 1);
}

// ---------------- K2: weight fragment tables ----------------
// Table layout: entry e = ((kc*16 + nt)*64 + lane)*8 + j
//   value = W[kc*32 + (lane>>4)*8 + j][nt*16 + (lane&15)] as bf16
__global__ void prep_kernel(const float* __restrict__ wv, const float* __restrict__ woff,
                            const float* __restrict__ wattn, const float* __restrict__ wout,
                            const float* __restrict__ boff, const float* __restrict__ battn,
                            short* __restrict__ tv, short* __restrict__ toa,
                            short* __restrict__ tout, float* __restrict__ biasOA) {
    int id = blockIdx.x * 256 + threadIdx.x;
    if (id < 3 * 65536) {
        int t = id >> 16;
        int e = id & 65535;
        int j = e & 7, l = (e >> 3) & 63, nt = (e >> 9) & 15, kc = e >> 13;
        int k = kc * 32 + ((l >> 4) << 3) + j;
        int col = nt * 16 + (l & 15);
        float v;
        if (t == 0)      v = wv[k * 256 + col];
        else if (t == 1) v = (col < 128) ? woff[k * 128 + col]
                               : (col < 192 ? wattn[k * 64 + (col - 128)] : 0.f);
        else             v = wout[k * 256 + col];
        short* dst = (t == 0) ? tv : (t == 1) ? toa : tout;
        dst[e] = f2bf(v);
    } else {
        int i = id - 3 * 65536;
        if (i < 192) biasOA[i] = (i < 128) ? boff[i] : battn[i - 128];
    }
}

// ---------------- GEMM: A(f32 MxK=256) x Btab(bf16) -> out ----------------
// MODE 0: out bf16, ld 256         (vproj)
// MODE 1: out f32, ld/ncols 192    (offattn)
// MODE 2: out f32 + bias + resid   (final)
template <int MODE>
__global__ __launch_bounds__(256)
void gemm_mfma(const float* __restrict__ A, const short* __restrict__ Btab,
               const float* __restrict__ bias, const float* __restrict__ resid,
               void* __restrict__ out, int M, int ncolsReal, int ldOut) {
    const int tid = threadIdx.x;
    const int l  = tid & 63;
    const int wv = tid >> 6;
    const int wr = wv >> 1, wc = wv & 1;
    const int lr = l & 15;
    const int lg = l >> 4;
    const int rowBase = blockIdx.x * 128 + wr * 64;
    const int colBase = blockIdx.y * 128 + wc * 64;

    f32x4 acc[4][4] = {};

    const float* ap[4];
    #pragma unroll
    for (int fm = 0; fm < 4; fm++) {
        int r = rowBase + fm * 16 + lr;
        if (r > M - 1) r = M - 1;
        ap[fm] = A + (size_t)r * 256 + lg * 8;
    }
    const int ntBase = blockIdx.y * 8 + wc * 4;
    const short* bp = Btab + ((size_t)ntBase * 64 + l) * 8;

    for (int kc = 0; kc < 8; kc++) {
        short8 af[4];
        #pragma unroll
        for (int fm = 0; fm < 4; fm++) {
            const float4* p = (const float4*)(ap[fm] + kc * 32);
            float4 x0 = p[0], x1 = p[1];
            af[fm][0] = f2bf(x0.x); af[fm][1] = f2bf(x0.y);
            af[fm][2] = f2bf(x0.z); af[fm][3] = f2bf(x0.w);
            af[fm][4] = f2bf(x1.x); af[fm][5] = f2bf(x1.y);
            af[fm][6] = f2bf(x1.z); af[fm][7] = f2bf(x1.w);
        }
        #pragma unroll
        for (int fn = 0; fn < 4; fn++) {
            short8 bf = *(const short8*)(bp + (size_t)kc * 8192 + fn * 512);
            #pragma unroll
            for (int fm = 0; fm < 4; fm++)
                acc[fm][fn] = __builtin_amdgcn_mfma_f32_16x16x32_bf16(af[fm], bf, acc[fm][fn], 0, 0, 0);
        }
    }

    #pragma unroll
    for (int fn = 0; fn < 4; fn++) {
        int c = colBase + fn * 16 + lr;
        float bv;
        if (MODE == 1) bv = (c < ncolsReal) ? bias[c] : 0.f;
        else           bv = bias[c];
        #pragma unroll
        for (int fm = 0; fm < 4; fm++) {
            int r0 = rowBase + fm * 16 + lg * 4;
            #pragma unroll
            for (int i = 0; i < 4; i++) {
                int r = r0 + i;
                if (r >= M) continue;
                float v = acc[fm][fn][i] + bv;
                if (MODE == 0) {
                    ((short*)out)[(size_t)r * ldOut + c] = f2bf(v);
                } else if (MODE == 1) {
                    if (c < ncolsReal) ((float*)out)[(size_t)r * ldOut + c] = v;
                } else {
                    ((float*)out)[(size_t)r * ldOut + c] = v + resid[(size_t)r * ldOut + c];
                }
            }
        }
    }
}

// ---------------- K4: fused softmax + bilinear sample + cam average ----------------
// unit = 8 lanes per (q,h); lane sub handles DH elems sub*4..sub*4+3.
__global__ __launch_bounds__(256)
void sample_kernel(const short* __restrict__ vproj, const float* __restrict__ offattn,
                   const float* __restrict__ refp, const float* __restrict__ hit,
                   const float* __restrict__ invcnt, float* __restrict__ slots) {
    int tid = threadIdx.x;
    int unit = blockIdx.x * 32 + (tid >> 3);
    int sub = tid & 7;
    int q = unit >> 3;
    int h = unit & 7;

    const float* oa = offattn + (size_t)q * 192;
    float ox[8], oy[8], aw[8];
    float m = -1e30f;
    #pragma unroll
    for (int p = 0; p < 8; p++) {
        ox[p] = oa[h * 16 + 2 * p];
        oy[p] = oa[h * 16 + 2 * p + 1];
        float lg = oa[128 + h * 8 + p];
        aw[p] = lg;
        m = fmaxf(m, lg);
    }
    float s = 0.f;
    #pragma unroll
    for (int p = 0; p < 8; p++) { aw[p] = __expf(aw[p] - m); s += aw[p]; }
    float is = 1.f / s;
    #pragma unroll
    for (int p = 0; p < 8; p++) aw[p] *= is;

    float a0 = 0.f, a1 = 0.f, a2 = 0.f, a3 = 0.f;
    const short* vb = vproj + h * 32 + sub * 4;

    for (int c = 0; c < CAMS; c++) {
        if (hit[c * QN + q] == 0.f) continue;
        const float* rp = refp + (size_t)(c * QN + q) * 8;
        float rx[4], ry[4];
        #pragma unroll
        for (int d = 0; d < 4; d++) {
            rx[d] = rp[2 * d]     * (float)WW - 0.5f;
            ry[d] = rp[2 * d + 1] * (float)HH - 0.5f;
        }
        const short* vc = vb + (size_t)c * (NV * 256);
        #pragma unroll
        for (int p = 0; p < 8; p++) {
            float x = rx[p & 3] + ox[p];
            float y = ry[p & 3] + oy[p];
            float xf = floorf(x), yf = floorf(y);
            float fx = x - xf, fy = y - yf;
            int x0 = (int)xf, y0 = (int)yf;
            float wp = aw[p];
            float w00 = (1.f - fx) * (1.f - fy) * wp;
            float w10 = fx * (1.f - fy) * wp;
            float w01 = (1.f - fx) * fy * wp;
            float w11 = fx * fy * wp;
            bool vx0 = (x0 >= 0) && (x0 < WW);
            bool vx1 = (x0 >= -1) && (x0 < WW - 1);
            bool vy0 = (y0 >= 0) && (y0 < HH);
            bool vy1 = (y0 >= -1) && (y0 < HH - 1);
            int base = y0 * WW + x0;
            if (vx0 && vy0) {
                short4v v = *(const short4v*)(vc + (size_t)base * 256);
                a0 += w00 * bf2f(v[0]); a1 += w00 * bf2f(v[1]);
                a2 += w00 * bf2f(v[2]); a3 += w00 * bf2f(v[3]);
            }
            if (vx1 && vy0) {
                short4v v = *(const short4v*)(vc + (size_t)(base + 1) * 256);
                a0 += w10 * bf2f(v[0]); a1 += w10 * bf2f(v[1]);
                a2 += w10 * bf2f(v[2]); a3 += w10 * bf2f(v[3]);
            }
            if (vx0 && vy1) {
                short4v v = *(const short4v*)(vc + (size_t)(base + WW) * 256);
                a0 += w01 * bf2f(v[0]); a1 += w01 * bf2f(v[1]);
                a2 += w01 * bf2f(v[2]); a3 += w01 * bf2f(v[3]);
            }
            if (vx1 && vy1) {
                short4v v = *(const short4v*)(vc + (size_t)(base + WW + 1) * 256);
                a0 += w11 * bf2f(v[0]); a1 += w11 * bf2f(v[1]);
                a2 += w11 * bf2f(v[2]); a3 += w11 * bf2f(v[3]);
            }
        }
    }
    float ic = invcnt[q];
    float* sp = slots + (size_t)q * 256 + h * 32 + sub * 4;
    float4 o; o.x = a0 * ic; o.y = a1 * ic; o.z = a2 * ic; o.w = a3 * ic;
    *(float4*)sp = o;
}

extern "C" void kernel_launch(void* const* d_in, const int* in_sizes, int n_in,
                              void* d_out, int out_size, void* d_ws, size_t ws_size,
                              hipStream_t stream) {
    const float* query   = (const float*)d_in[0];
    const float* value   = (const float*)d_in[2];
    const float* refp    = (const float*)d_in[3];
    const void*  mask    = d_in[4];
    const float* w_value = (const float*)d_in[7];
    const float* b_value = (const float*)d_in[8];
    const float* w_off   = (const float*)d_in[9];
    const float* b_off   = (const float*)d_in[10];
    const float* w_attn  = (const float*)d_in[11];
    const float* b_attn  = (const float*)d_in[12];
    const float* w_out   = (const float*)d_in[13];
    const float* b_out   = (const float*)d_in[14];
    float* out = (float*)d_out;

    char* w = (char*)d_ws;
    size_t o = 0;
    auto carve = [&](size_t bytes) { size_t r = o; o = (o + bytes + 255) & ~(size_t)255; return r; };
    int*   flag    = (int*)  (w + carve(4));
    float* hitv    = (float*)(w + carve(sizeof(float) * CAMS * QN));
    float* invc    = (float*)(w + carve(sizeof(float) * QN));
    short* tv      = (short*)(w + carve(2 * 65536));
    short* toa     = (short*)(w + carve(2 * 65536));
    short* tout    = (short*)(w + carve(2 * 65536));
    float* biasOA  = (float*)(w + carve(sizeof(float) * 192));
    short* vproj   = (short*)(w + carve((size_t)2 * MROW * 256));
    float* offattn = (float*)(w + carve(sizeof(float) * QN * 192));
    float* slots   = (float*)(w + carve(sizeof(float) * QN * 256));

    detect_kernel<<<1, 256, 0, stream>>>((const unsigned char*)mask, flag);
    prep_kernel<<<769, 256, 0, stream>>>(w_value, w_off, w_attn, w_out, b_off, b_attn,
                                         tv, toa, tout, biasOA);
    hit_kernel<<<(QN + 255) / 256, 256, 0, stream>>>(mask, flag, hitv, invc);

    gemm_mfma<0><<<dim3((MROW + 127) / 128, 2), 256, 0, stream>>>(
        value, tv, b_value, nullptr, vproj, MROW, 256, 256);
    gemm_mfma<1><<<dim3((QN + 127) / 128, 2), 256, 0, stream>>>(
        query, toa, biasOA, nullptr, offattn, QN, 192, 192);

    sample_kernel<<<(QN * 8 * 8) / 256, 256, 0, stream>>>(
        vproj, offattn, refp, hitv, invc, slots);

    gemm_mfma<2><<<dim3((QN + 127) / 128, 2), 256, 0, stream>>>(
        slots, tout, b_out, query, out, QN, 256, 256);
}